// Round 6
// baseline (13798.807 us; speedup 1.0000x reference)
//
#include <hip/hip_runtime.h>

#define T_STEPS 512
#define E_EDGES 128
#define NN 32
#define HH 256
#define G4 1024   // 4*H
#define NWG 64    // 2 dirs * 32 slots
#define TPB 256
#define FSTRIDE 16  // ints between flags (64B cachelines)

__device__ __forceinline__ float fsig(float x) {
  x = fminf(fmaxf(x, -30.f), 30.f);
  return 1.f / (1.f + __expf(-x));
}
__device__ __forceinline__ float ftanh(float x) {
  float xc = fminf(fmaxf(x, -15.f), 15.f);
  float e = __expf(2.f * xc);
  return (e - 1.f) / (e + 1.f);
}

// ---------------- per-step edge counts (denominators) ----------------
__global__ __launch_bounds__(128) void count_kernel(const int* __restrict__ src,
    const int* __restrict__ dst, float* __restrict__ cS, float* __restrict__ cD) {
  __shared__ int ls[NN], ld[NN];
  int t = blockIdx.x;
  if (threadIdx.x < NN) { ls[threadIdx.x] = 0; ld[threadIdx.x] = 0; }
  __syncthreads();
  atomicAdd(&ls[src[t * E_EDGES + threadIdx.x]], 1);
  atomicAdd(&ld[dst[t * E_EDGES + threadIdx.x]], 1);
  __syncthreads();
  if (threadIdx.x < NN) {
    cS[t * NN + threadIdx.x] = (float)ls[threadIdx.x];
    cD[t * NN + threadIdx.x] = (float)ld[threadIdx.x];
  }
}

// ---------------- feed-forward gates GEMM -----------------------------
// Gx[lt][e][k] = b[k] + sum_m In[tsrc][e][m] * W[k][m]   ([e][k] layout)
template <int M>
__global__ __launch_bounds__(256) void gates_gemm(
    const float* __restrict__ In, const float* __restrict__ W,
    const float* __restrict__ b, float* __restrict__ Gx, int reverse, int t0) {
  __shared__ float Wsh[64][68];
  __shared__ float Xsh[128][68];
  const int tid = threadIdx.x;
  const int k0 = blockIdx.x * 64;
  const int lt = blockIdx.y;
  const int t = t0 + lt;
  const int tsrc = reverse ? (T_STEPS - 1 - t) : t;
  const float* Inb = In + (size_t)tsrc * E_EDGES * M;

  const int ty = tid >> 4;
  const int tx = tid & 15;

  float acc[4][8];
#pragma unroll
  for (int i = 0; i < 4; ++i) {
    float bv = b[k0 + ty * 4 + i];
#pragma unroll
    for (int j = 0; j < 8; ++j) acc[i][j] = bv;
  }

  for (int m0 = 0; m0 < M; m0 += 64) {
    __syncthreads();
#pragma unroll
    for (int p = 0; p < 4; ++p) {
      int r = (tid >> 4) + 16 * p;
      int c4 = tid & 15;
      float4 v = *(const float4*)(W + (size_t)(k0 + r) * M + m0 + c4 * 4);
      *(float4*)(&Wsh[r][c4 * 4]) = v;
    }
#pragma unroll
    for (int p = 0; p < 8; ++p) {
      int r = (tid >> 4) + 16 * p;
      int c4 = tid & 15;
      float4 v = *(const float4*)(Inb + (size_t)r * M + m0 + c4 * 4);
      *(float4*)(&Xsh[r][c4 * 4]) = v;
    }
    __syncthreads();
#pragma unroll 8
    for (int mm = 0; mm < 64; ++mm) {
      float wv[4], xv[8];
#pragma unroll
      for (int i = 0; i < 4; ++i) wv[i] = Wsh[ty * 4 + i][mm];
#pragma unroll
      for (int j = 0; j < 8; ++j) xv[j] = Xsh[tx + 16 * j][mm];
#pragma unroll
      for (int i = 0; i < 4; ++i)
#pragma unroll
        for (int j = 0; j < 8; ++j) acc[i][j] = __fmaf_rn(wv[i], xv[j], acc[i][j]);
    }
  }
#pragma unroll
  for (int j = 0; j < 8; ++j) {
    float4 v = make_float4(acc[0][j], acc[1][j], acc[2][j], acc[3][j]);
    *(float4*)(Gx + ((size_t)lt * E_EDGES + tx + 16 * j) * G4 + k0 + ty * 4) = v;
  }
}

// ---------------- recurrence (cooperative, fence-free flag barrier) ---
// hn exchange uses relaxed AGENT-scope atomics (coherent at the LLC): no
// acquire/release fences -> no per-step buffer_inv / buffer_wbl2, L2 stays
// warm for the Gx/src/dst/count streams. Ordering: __syncthreads drains
// vmcnt(0) (sc1 stores acked at coherence point) before the flag store.
__global__ __launch_bounds__(TPB) void recur_kernel(
    const float* __restrict__ GxF, const float* __restrict__ GxB,
    const float* __restrict__ WhhF, const float* __restrict__ WhhB,
    const int* __restrict__ src, const int* __restrict__ dst,
    const float* __restrict__ cS, const float* __restrict__ cD,
    float* hnG, float* cnG, float* outBase,
    int t0, int nsteps, int roundBase, int* flags) {
  __shared__ float4 hnS4[NN * 64];   // 32 KB  (hn, rows = node), XOR-swizzled
  __shared__ float4 Ws4[32 * 64];    // 32 KB  (Whh slice, rows = gc), swizzled
  __shared__ float zP[4][NN][33];    // K-split partials
  __shared__ float zF[NN][33];
  __shared__ float cnL[NN][9];
  __shared__ float hAcc[NN][9];
  __shared__ float cAcc[NN][9];

  const int tid = threadIdx.x;
  const int wg = blockIdx.x;
  const int dir = wg >> 5;
  const int slot = wg & 31;
  const int j0 = slot * 8;
  const float* Gx = dir ? GxB : GxF;
  const float* Whh = dir ? WhhB : WhhF;
  const int* seA = dir ? dst : src;
  const int* deA = dir ? src : dst;
  const float* cA = dir ? cS : cD;
  float* cnGd = cnG + (size_t)dir * NN * HH;

  // --- stage Whh slice (swizzled), once ---
  {
    int gc = tid >> 3;                       // 0..31
    int g = gc >> 3, jj = gc & 7;
    const float* wr = Whh + ((size_t)(g * HH) + j0 + jj) * HH;
    int c0 = (tid & 7) * 8;
#pragma unroll
    for (int p = 0; p < 8; ++p) {
      int c4 = c0 + p;
      Ws4[gc * 64 + (c4 ^ (gc >> 2))] = *(const float4*)(wr + c4 * 4);
    }
  }
  { // cell state + accumulators
    int n = tid >> 3, jj = tid & 7;
    cnL[n][jj] = cnGd[n * HH + j0 + jj];
    hAcc[n][jj] = 0.f; cAcc[n][jj] = 0.f;
  }
  __syncthreads();

  const int lane = tid & 63;
  const int wv = tid >> 6;       // wave -> K range [wv*64, +64)
  const int ng = lane >> 3;      // nodes 4ng..4ng+3
  const int gg = lane & 7;       // gc 4gg..4gg+3
  const int e = tid >> 1, jh = tid & 1;  // edge phase

  for (int rl = 0; rl < nsteps; ++rl) {
    const int r = t0 + rl;
    const int tv = dir ? (T_STEPS - 1 - r) : r;

    // --- P0: issue step-invariant loads (hide latency under poll) ---
    const int sec = seA[tv * E_EDGES + e];
    const int dec = deA[tv * E_EDGES + e];
    const float cntc = cA[tv * NN + (tid >> 3)];
    const float* gxe = Gx + ((size_t)rl * E_EDGES + e) * G4 + j0 + jh * 4;
    float4 gxi = *(const float4*)(gxe + 0 * HH);
    float4 gxf = *(const float4*)(gxe + 1 * HH);
    float4 gxg = *(const float4*)(gxe + 2 * HH);
    float4 gxo = *(const float4*)(gxe + 3 * HH);

    // --- P1: poll (relaxed coherent spin; no fence needed) ---
    if (rl > 0 && tid < 64) {
      const int target = roundBase + rl;
      int* fp = flags + (dir * 32 + (tid & 31)) * FSTRIDE;
      int guard = 0;
      for (;;) {
        int fv = __hip_atomic_load(fp, __ATOMIC_RELAXED, __HIP_MEMORY_SCOPE_AGENT);
        if (__all(fv >= target)) break;
        __builtin_amdgcn_s_sleep(1);
        if (++guard > (1 << 22)) break;
      }
    }
    __syncthreads();

    // --- P2: stage hn via coherent 8B atomic loads -> swizzled LDS ---
    {
      const unsigned long long* hnRd = (const unsigned long long*)
          (hnG + (size_t)((r & 1) * 2 + dir) * NN * HH);
      float2* hnS2 = (float2*)hnS4;
#pragma unroll
      for (int p = 0; p < 16; ++p) {
        int idx = tid + 256 * p;        // u64 index, 0..4095
        int n = idx >> 7, c2 = idx & 127;
        unsigned long long uv = __hip_atomic_load(hnRd + (size_t)n * 128 + c2,
            __ATOMIC_RELAXED, __HIP_MEMORY_SCOPE_AGENT);
        union { unsigned long long u; float2 f; } cv; cv.u = uv;
        int c4 = c2 >> 1, half = c2 & 1;
        hnS2[(n * 64 + (c4 ^ (n >> 2))) * 2 + half] = cv.f;
      }
    }
    __syncthreads();

    // --- P3: z partials, 4x4 block, K-split across 4 waves ---
    {
      float za[4][4];
#pragma unroll
      for (int i = 0; i < 4; ++i)
#pragma unroll
        for (int j = 0; j < 4; ++j) za[i][j] = 0.f;
      const int kb = wv * 16;
#pragma unroll 4
      for (int c4 = kb; c4 < kb + 16; ++c4) {
        float4 h[4], w[4];
#pragma unroll
        for (int i = 0; i < 4; ++i) h[i] = hnS4[(4 * ng + i) * 64 + (c4 ^ ng)];
#pragma unroll
        for (int j = 0; j < 4; ++j) w[j] = Ws4[(4 * gg + j) * 64 + (c4 ^ gg)];
#pragma unroll
        for (int i = 0; i < 4; ++i)
#pragma unroll
          for (int j = 0; j < 4; ++j) {
            za[i][j] = __fmaf_rn(h[i].x, w[j].x, za[i][j]);
            za[i][j] = __fmaf_rn(h[i].y, w[j].y, za[i][j]);
            za[i][j] = __fmaf_rn(h[i].z, w[j].z, za[i][j]);
            za[i][j] = __fmaf_rn(h[i].w, w[j].w, za[i][j]);
          }
      }
#pragma unroll
      for (int i = 0; i < 4; ++i)
#pragma unroll
        for (int j = 0; j < 4; ++j) zP[wv][4 * ng + i][4 * gg + j] = za[i][j];
    }
    __syncthreads();

    // --- P4: reduce partials -> zF ---
    {
      int n = tid >> 3, c0 = (tid & 7) * 4;
#pragma unroll
      for (int u = 0; u < 4; ++u) {
        zF[n][c0 + u] = zP[0][n][c0 + u] + zP[1][n][c0 + u] +
                        zP[2][n][c0 + u] + zP[3][n][c0 + u];
      }
    }
    __syncthreads();

    // --- P5: edge phase: gates -> cell -> per-edge h (out store deferred) ---
    float hq[4];
    {
      const float* zr = zF[sec];
      const float* cr = cnL[sec];
      const float gi4[4] = {gxi.x, gxi.y, gxi.z, gxi.w};
      const float gf4[4] = {gxf.x, gxf.y, gxf.z, gxf.w};
      const float gg4[4] = {gxg.x, gxg.y, gxg.z, gxg.w};
      const float go4[4] = {gxo.x, gxo.y, gxo.z, gxo.w};
#pragma unroll
      for (int u = 0; u < 4; ++u) {
        int jj = jh * 4 + u;
        float gi = gi4[u] + zr[0 + jj];
        float gf = gf4[u] + zr[8 + jj];
        float gv = gg4[u] + zr[16 + jj];
        float go = go4[u] + zr[24 + jj];
        float cv = fsig(gf) * cr[jj] + fsig(gi) * ftanh(gv);
        float hv = fsig(go) * ftanh(cv);
        hq[u] = hv;
        atomicAdd(&hAcc[dec][jj], hv);
        atomicAdd(&cAcc[dec][jj], cv);
      }
    }
    __syncthreads();

    // --- P6: scatter-mean -> coherent hn stores; flag after drain ---
    {
      int n = tid >> 3, jj = tid & 7;
      float* hnWr = hnG + (size_t)(((r + 1) & 1) * 2 + dir) * NN * HH;
      float rd = 1.f / fmaxf(cntc, 1.f);
      float hnv = hAcc[n][jj] * rd;
      __hip_atomic_store(hnWr + n * HH + j0 + jj, hnv,
                         __ATOMIC_RELAXED, __HIP_MEMORY_SCOPE_AGENT);
      cnL[n][jj] = cAcc[n][jj] * rd;
      hAcc[n][jj] = 0.f; cAcc[n][jj] = 0.f;
    }
    __syncthreads();   // drains vmcnt(0): hn stores acked at coherence point
    if (tid == 0) {
      __hip_atomic_store(flags + (dir * 32 + slot) * FSTRIDE, roundBase + rl + 1,
                         __ATOMIC_RELAXED, __HIP_MEMORY_SCOPE_AGENT);
    }

    // --- P7: out store (fire-and-forget; drains during next poll) ---
    {
      int tw = dir ? (T_STEPS - 1 - r) : r;
      *(float4*)(outBase + ((size_t)tw * E_EDGES + e) * 512 + dir * 256 + j0 + jh * 4)
          = make_float4(hq[0], hq[1], hq[2], hq[3]);
    }
  }

  { // persist cell state for next chunk
    int n = tid >> 3, jj = tid & 7;
    cnGd[n * HH + j0 + jj] = cnL[n][jj];
  }
}

// ---------------- host launcher ---------------------------------------
extern "C" void kernel_launch(void* const* d_in, const int* in_sizes, int n_in,
                              void* d_out, int out_size, void* d_ws, size_t ws_size,
                              hipStream_t stream) {
  const float* x = (const float*)d_in[0];
  const float* Wih0 = (const float*)d_in[1];
  const float* Whh0 = (const float*)d_in[2];
  const float* b0 = (const float*)d_in[3];
  const float* Wih1 = (const float*)d_in[4];
  const float* Whh1 = (const float*)d_in[5];
  const float* b1 = (const float*)d_in[6];
  const int* src = (const int*)d_in[7];
  const int* dst = (const int*)d_in[8];
  float* out = (float*)d_out;

  const size_t outElems = (size_t)T_STEPS * E_EDGES * 512;
  int C = 512;
  while (C >= 1) {
    size_t need = (2 * (size_t)C * G4 * E_EDGES + outElems + 6 * (size_t)NN * HH +
                   2 * (size_t)T_STEPS * NN + NWG * FSTRIDE + 256) * sizeof(float);
    if (need <= ws_size) break;
    C >>= 1;
  }
  if (C < 1) return;

  float* GxF = (float*)d_ws;
  float* GxB = GxF + (size_t)C * G4 * E_EDGES;
  float* out0 = GxB + (size_t)C * G4 * E_EDGES;
  float* hnG = out0 + outElems;                 // 4 * NN*HH (2 parities x 2 dirs)
  float* cnG = hnG + 4 * NN * HH;               // 2 * NN*HH
  float* cSt = cnG + 2 * NN * HH;
  float* cDt = cSt + (size_t)T_STEPS * NN;
  int* flags = (int*)(cDt + (size_t)T_STEPS * NN);

  (void)hipMemsetAsync(flags, 0, NWG * FSTRIDE * sizeof(int), stream);
  count_kernel<<<dim3(T_STEPS), 128, 0, stream>>>(src, dst, cSt, cDt);

  for (int layer = 0; layer < 2; ++layer) {
    const float* Wih = layer ? Wih1 : Wih0;
    const float* Whh = layer ? Whh1 : Whh0;
    const float* bb = layer ? b1 : b0;
    const float* In = layer ? out0 : x;
    float* outT = layer ? out : out0;
    (void)hipMemsetAsync(hnG, 0, 4 * NN * HH * sizeof(float), stream);
    (void)hipMemsetAsync(cnG, 0, 2 * NN * HH * sizeof(float), stream);
    for (int t0 = 0; t0 < T_STEPS; t0 += C) {
      if (layer == 0) {
        gates_gemm<64><<<dim3(16, C), 256, 0, stream>>>(In, Wih, bb, GxF, 0, t0);
        gates_gemm<64><<<dim3(16, C), 256, 0, stream>>>(In, Wih + (size_t)G4 * 64, bb + G4, GxB, 1, t0);
      } else {
        gates_gemm<512><<<dim3(16, C), 256, 0, stream>>>(In, Wih, bb, GxF, 0, t0);
        gates_gemm<512><<<dim3(16, C), 256, 0, stream>>>(In, Wih + (size_t)G4 * 512, bb + G4, GxB, 1, t0);
      }
      const float* gxF = GxF; const float* gxB = GxB;
      const float* whF = Whh; const float* whB = Whh + (size_t)G4 * HH;
      const int* psrc = src; const int* pdst = dst;
      const float* pcS = cSt; const float* pcD = cDt;
      float* phn = hnG; float* pcn = cnG; float* pout = outT;
      int a_t0 = t0, a_ns = C, a_rb = layer * T_STEPS + t0;
      int* pfl = flags;
      void* args[15] = {&gxF, &gxB, &whF, &whB, &psrc, &pdst, &pcS, &pcD,
                        &phn, &pcn, &pout, &a_t0, &a_ns, &a_rb, &pfl};
      hipLaunchCooperativeKernel((const void*)recur_kernel, dim3(NWG), dim3(TPB),
                                 args, 0, stream);
    }
  }
}

// Round 7
// 13729.997 us; speedup vs baseline: 1.0050x; 1.0050x over previous
//
#include <hip/hip_runtime.h>

#define T_STEPS 512
#define E_EDGES 128
#define NN 32
#define HH 256
#define G4 1024   // 4*H
#define NWG 64    // 2 dirs * 32 slots
#define TPB 256
#define FSTRIDE 16  // ints between flags (64B cachelines)

__device__ __forceinline__ float fsig(float x) {
  x = fminf(fmaxf(x, -30.f), 30.f);
  return 1.f / (1.f + __expf(-x));
}
__device__ __forceinline__ float ftanh(float x) {
  float xc = fminf(fmaxf(x, -15.f), 15.f);
  float e = __expf(2.f * xc);
  return (e - 1.f) / (e + 1.f);
}

// ---------------- per-step edge counts (denominators) ----------------
__global__ __launch_bounds__(128) void count_kernel(const int* __restrict__ src,
    const int* __restrict__ dst, float* __restrict__ cS, float* __restrict__ cD) {
  __shared__ int ls[NN], ld[NN];
  int t = blockIdx.x;
  if (threadIdx.x < NN) { ls[threadIdx.x] = 0; ld[threadIdx.x] = 0; }
  __syncthreads();
  atomicAdd(&ls[src[t * E_EDGES + threadIdx.x]], 1);
  atomicAdd(&ld[dst[t * E_EDGES + threadIdx.x]], 1);
  __syncthreads();
  if (threadIdx.x < NN) {
    cS[t * NN + threadIdx.x] = (float)ls[threadIdx.x];
    cD[t * NN + threadIdx.x] = (float)ld[threadIdx.x];
  }
}

// ---------------- feed-forward gates GEMM -----------------------------
// Output layout: Gx[slot][lt][gate][e][jj8]  (slot = channel-octet owner WG)
// -> each recur WG reads ONE contiguous 16KB block per step.
template <int M>
__global__ __launch_bounds__(256) void gates_gemm(
    const float* __restrict__ In, const float* __restrict__ W,
    const float* __restrict__ b, float* __restrict__ Gx, int reverse, int t0,
    int Cs) {
  __shared__ float Wsh[64][68];
  __shared__ float Xsh[128][68];
  const int tid = threadIdx.x;
  const int k0 = blockIdx.x * 64;
  const int lt = blockIdx.y;
  const int t = t0 + lt;
  const int tsrc = reverse ? (T_STEPS - 1 - t) : t;
  const float* Inb = In + (size_t)tsrc * E_EDGES * M;

  const int ty = tid >> 4;  // k-quad group: k = k0 + ty*4 + i
  const int tx = tid & 15;  // e group: e = tx + 16*j

  float acc[4][8];
#pragma unroll
  for (int i = 0; i < 4; ++i) {
    float bv = b[k0 + ty * 4 + i];
#pragma unroll
    for (int j = 0; j < 8; ++j) acc[i][j] = bv;
  }

  for (int m0 = 0; m0 < M; m0 += 64) {
    __syncthreads();
#pragma unroll
    for (int p = 0; p < 4; ++p) {
      int r = (tid >> 4) + 16 * p;
      int c4 = tid & 15;
      float4 v = *(const float4*)(W + (size_t)(k0 + r) * M + m0 + c4 * 4);
      *(float4*)(&Wsh[r][c4 * 4]) = v;
    }
#pragma unroll
    for (int p = 0; p < 8; ++p) {
      int r = (tid >> 4) + 16 * p;
      int c4 = tid & 15;
      float4 v = *(const float4*)(Inb + (size_t)r * M + m0 + c4 * 4);
      *(float4*)(&Xsh[r][c4 * 4]) = v;
    }
    __syncthreads();
    // m-vectorized inner loop: float4 LDS reads (w: wave-broadcast, x: 2-way)
#pragma unroll 4
    for (int mm4 = 0; mm4 < 16; ++mm4) {
      float4 wv4[4], xv4[8];
#pragma unroll
      for (int i = 0; i < 4; ++i) wv4[i] = *(const float4*)(&Wsh[ty * 4 + i][mm4 * 4]);
#pragma unroll
      for (int j = 0; j < 8; ++j) xv4[j] = *(const float4*)(&Xsh[tx + 16 * j][mm4 * 4]);
#pragma unroll
      for (int i = 0; i < 4; ++i)
#pragma unroll
        for (int j = 0; j < 8; ++j) {
          acc[i][j] = __fmaf_rn(wv4[i].x, xv4[j].x, acc[i][j]);
          acc[i][j] = __fmaf_rn(wv4[i].y, xv4[j].y, acc[i][j]);
          acc[i][j] = __fmaf_rn(wv4[i].z, xv4[j].z, acc[i][j]);
          acc[i][j] = __fmaf_rn(wv4[i].w, xv4[j].w, acc[i][j]);
        }
    }
  }
  // store to per-slot-contiguous layout
  {
    const int kb = k0 + ty * 4;
    const int gate = kb >> 8;
    const int ch = kb & 255;
    const int slot = ch >> 3;
    const int jj0 = ch & 7;  // 0 or 4
    float* gbase = Gx + ((((size_t)slot * Cs + lt) * 4 + gate) * E_EDGES) * 8 + jj0;
#pragma unroll
    for (int j = 0; j < 8; ++j) {
      int e = tx + 16 * j;
      *(float4*)(gbase + (size_t)e * 8) =
          make_float4(acc[0][j], acc[1][j], acc[2][j], acc[3][j]);
    }
  }
}

// ---------------- recurrence (cooperative, fence-free flag barrier) ---
__global__ __launch_bounds__(TPB) void recur_kernel(
    const float* __restrict__ GxF, const float* __restrict__ GxB,
    const float* __restrict__ WhhF, const float* __restrict__ WhhB,
    const int* __restrict__ src, const int* __restrict__ dst,
    const float* __restrict__ cS, const float* __restrict__ cD,
    float* hnG, float* cnG, float* outBase,
    int t0, int nsteps, int roundBase, int* flags) {
  __shared__ float4 hnS4[NN * 64];   // 32 KB  (hn, rows = node), XOR-swizzled
  __shared__ float4 Ws4[32 * 64];    // 32 KB  (Whh slice, rows = gc), swizzled
  __shared__ float zP[4][NN][33];    // K-split partials
  __shared__ float zF[NN][33];
  __shared__ float cnL[NN][9];
  __shared__ float hAcc[NN][9];
  __shared__ float cAcc[NN][9];

  const int tid = threadIdx.x;
  const int wg = blockIdx.x;
  const int dir = wg >> 5;
  const int slot = wg & 31;
  const int j0 = slot * 8;
  const float* Gx = dir ? GxB : GxF;
  const float* Whh = dir ? WhhB : WhhF;
  const int* seA = dir ? dst : src;
  const int* deA = dir ? src : dst;
  const float* cA = dir ? cS : cD;
  float* cnGd = cnG + (size_t)dir * NN * HH;

  // --- stage Whh slice (swizzled), once ---
  {
    int gc = tid >> 3;                       // 0..31
    int g = gc >> 3, jj = gc & 7;
    const float* wr = Whh + ((size_t)(g * HH) + j0 + jj) * HH;
    int c0 = (tid & 7) * 8;
#pragma unroll
    for (int p = 0; p < 8; ++p) {
      int c4 = c0 + p;
      Ws4[gc * 64 + (c4 ^ (gc >> 2))] = *(const float4*)(wr + c4 * 4);
    }
  }
  { // cell state + accumulators
    int n = tid >> 3, jj = tid & 7;
    cnL[n][jj] = cnGd[n * HH + j0 + jj];
    hAcc[n][jj] = 0.f; cAcc[n][jj] = 0.f;
  }
  __syncthreads();

  const int lane = tid & 63;
  const int wv = tid >> 6;       // wave -> K range [wv*64, +64)
  const int ng = lane >> 3;      // nodes 4ng..4ng+3
  const int gg = lane & 7;       // gc 4gg..4gg+3
  const int e = tid >> 1, jh = tid & 1;  // edge phase

  // WG's contiguous Gx block: Gx + slot*nsteps*4096 + rl*4096; thread reads
  // byte offset tid*16 within each 4KB gate sub-block -> fully coalesced.
  const float* gxWG = Gx + (size_t)slot * nsteps * 4096 + (e * 8 + jh * 4);

  // --- prefetch step 0 ---
  int sec, dec; float cntc; float4 gxi, gxf, gxg, gxo;
  {
    int tv = dir ? (T_STEPS - 1 - t0) : t0;
    sec = seA[tv * E_EDGES + e];
    dec = deA[tv * E_EDGES + e];
    cntc = cA[tv * NN + (tid >> 3)];
    const float* gp = gxWG;  // rl = 0
    gxi = *(const float4*)(gp + 0 * 1024);
    gxf = *(const float4*)(gp + 1 * 1024);
    gxg = *(const float4*)(gp + 2 * 1024);
    gxo = *(const float4*)(gp + 3 * 1024);
  }

  for (int rl = 0; rl < nsteps; ++rl) {
    const int r = t0 + rl;

    // --- P1: poll (relaxed coherent spin) ---
    if (rl > 0 && tid < 64) {
      const int target = roundBase + rl;
      int* fp = flags + (dir * 32 + (tid & 31)) * FSTRIDE;
      int guard = 0;
      for (;;) {
        int fv = __hip_atomic_load(fp, __ATOMIC_RELAXED, __HIP_MEMORY_SCOPE_AGENT);
        if (__all(fv >= target)) break;
        __builtin_amdgcn_s_sleep(1);
        if (++guard > (1 << 22)) break;
      }
    }
    __syncthreads();

    // --- P2: stage hn via coherent 8B atomic loads -> swizzled LDS ---
    {
      const unsigned long long* hnRd = (const unsigned long long*)
          (hnG + (size_t)((r & 1) * 2 + dir) * NN * HH);
      float2* hnS2 = (float2*)hnS4;
#pragma unroll
      for (int p = 0; p < 16; ++p) {
        int idx = tid + 256 * p;        // u64 index, 0..4095
        int n = idx >> 7, c2 = idx & 127;
        unsigned long long uv = __hip_atomic_load(hnRd + (size_t)n * 128 + c2,
            __ATOMIC_RELAXED, __HIP_MEMORY_SCOPE_AGENT);
        union { unsigned long long u; float2 f; } cv; cv.u = uv;
        int c4 = c2 >> 1, half = c2 & 1;
        hnS2[(n * 64 + (c4 ^ (n >> 2))) * 2 + half] = cv.f;
      }
    }
    __syncthreads();

    // --- P3: z partials, 4x4 block, K-split across 4 waves ---
    {
      float za[4][4];
#pragma unroll
      for (int i = 0; i < 4; ++i)
#pragma unroll
        for (int j = 0; j < 4; ++j) za[i][j] = 0.f;
      const int kb = wv * 16;
#pragma unroll 4
      for (int c4 = kb; c4 < kb + 16; ++c4) {
        float4 h[4], w[4];
#pragma unroll
        for (int i = 0; i < 4; ++i) h[i] = hnS4[(4 * ng + i) * 64 + (c4 ^ ng)];
#pragma unroll
        for (int j = 0; j < 4; ++j) w[j] = Ws4[(4 * gg + j) * 64 + (c4 ^ gg)];
#pragma unroll
        for (int i = 0; i < 4; ++i)
#pragma unroll
          for (int j = 0; j < 4; ++j) {
            za[i][j] = __fmaf_rn(h[i].x, w[j].x, za[i][j]);
            za[i][j] = __fmaf_rn(h[i].y, w[j].y, za[i][j]);
            za[i][j] = __fmaf_rn(h[i].z, w[j].z, za[i][j]);
            za[i][j] = __fmaf_rn(h[i].w, w[j].w, za[i][j]);
          }
      }
#pragma unroll
      for (int i = 0; i < 4; ++i)
#pragma unroll
        for (int j = 0; j < 4; ++j) zP[wv][4 * ng + i][4 * gg + j] = za[i][j];
    }
    __syncthreads();

    // --- P4: reduce partials -> zF ---
    {
      int n = tid >> 3, c0 = (tid & 7) * 4;
#pragma unroll
      for (int u = 0; u < 4; ++u) {
        zF[n][c0 + u] = zP[0][n][c0 + u] + zP[1][n][c0 + u] +
                        zP[2][n][c0 + u] + zP[3][n][c0 + u];
      }
    }
    __syncthreads();

    // --- P5: edge phase (consumes prefetched regs) ---
    float hq[4];
    {
      const float* zr = zF[sec];
      const float* cr = cnL[sec];
      const float gi4[4] = {gxi.x, gxi.y, gxi.z, gxi.w};
      const float gf4[4] = {gxf.x, gxf.y, gxf.z, gxf.w};
      const float gg4[4] = {gxg.x, gxg.y, gxg.z, gxg.w};
      const float go4[4] = {gxo.x, gxo.y, gxo.z, gxo.w};
#pragma unroll
      for (int u = 0; u < 4; ++u) {
        int jj = jh * 4 + u;
        float gi = gi4[u] + zr[0 + jj];
        float gf = gf4[u] + zr[8 + jj];
        float gv = gg4[u] + zr[16 + jj];
        float go = go4[u] + zr[24 + jj];
        float cv = fsig(gf) * cr[jj] + fsig(gi) * ftanh(gv);
        float hv = fsig(go) * ftanh(cv);
        hq[u] = hv;
        atomicAdd(&hAcc[dec][jj], hv);
        atomicAdd(&cAcc[dec][jj], cv);
      }
    }
    __syncthreads();

    // --- P6: scatter-mean -> coherent hn stores; flag after drain ---
    const int decU = dec;  // keep current-step dst for nothing else; rotate below
    {
      int n = tid >> 3, jj = tid & 7;
      float* hnWr = hnG + (size_t)(((r + 1) & 1) * 2 + dir) * NN * HH;
      float rd = 1.f / fmaxf(cntc, 1.f);
      float hnv = hAcc[n][jj] * rd;
      __hip_atomic_store(hnWr + n * HH + j0 + jj, hnv,
                         __ATOMIC_RELAXED, __HIP_MEMORY_SCOPE_AGENT);
      cnL[n][jj] = cAcc[n][jj] * rd;
      hAcc[n][jj] = 0.f; cAcc[n][jj] = 0.f;
    }
    __syncthreads();   // drains vmcnt(0): hn stores acked at coherence point
    if (tid == 0) {
      __hip_atomic_store(flags + (dir * 32 + slot) * FSTRIDE, roundBase + rl + 1,
                         __ATOMIC_RELAXED, __HIP_MEMORY_SCOPE_AGENT);
    }
    (void)decU;

    // --- P7: out store (fire-and-forget) + prefetch step rl+1 ---
    {
      int tw = dir ? (T_STEPS - 1 - r) : r;
      *(float4*)(outBase + ((size_t)tw * E_EDGES + e) * 512 + dir * 256 + j0 + jh * 4)
          = make_float4(hq[0], hq[1], hq[2], hq[3]);
    }
    {
      int rc = (rl + 1 < nsteps) ? (rl + 1) : rl;
      int tv = dir ? (T_STEPS - 1 - (t0 + rc)) : (t0 + rc);
      sec = seA[tv * E_EDGES + e];
      dec = deA[tv * E_EDGES + e];
      cntc = cA[tv * NN + (tid >> 3)];
      const float* gp = gxWG + (size_t)rc * 4096;
      gxi = *(const float4*)(gp + 0 * 1024);
      gxf = *(const float4*)(gp + 1 * 1024);
      gxg = *(const float4*)(gp + 2 * 1024);
      gxo = *(const float4*)(gp + 3 * 1024);
    }
  }

  { // persist cell state for next chunk
    int n = tid >> 3, jj = tid & 7;
    cnGd[n * HH + j0 + jj] = cnL[n][jj];
  }
}

// ---------------- host launcher ---------------------------------------
extern "C" void kernel_launch(void* const* d_in, const int* in_sizes, int n_in,
                              void* d_out, int out_size, void* d_ws, size_t ws_size,
                              hipStream_t stream) {
  const float* x = (const float*)d_in[0];
  const float* Wih0 = (const float*)d_in[1];
  const float* Whh0 = (const float*)d_in[2];
  const float* b0 = (const float*)d_in[3];
  const float* Wih1 = (const float*)d_in[4];
  const float* Whh1 = (const float*)d_in[5];
  const float* b1 = (const float*)d_in[6];
  const int* src = (const int*)d_in[7];
  const int* dst = (const int*)d_in[8];
  float* out = (float*)d_out;

  const size_t outElems = (size_t)T_STEPS * E_EDGES * 512;
  int C = 512;
  while (C >= 1) {
    size_t need = (2 * (size_t)C * G4 * E_EDGES + outElems + 6 * (size_t)NN * HH +
                   2 * (size_t)T_STEPS * NN + NWG * FSTRIDE + 256) * sizeof(float);
    if (need <= ws_size) break;
    C >>= 1;
  }
  if (C < 1) return;

  float* GxF = (float*)d_ws;
  float* GxB = GxF + (size_t)C * G4 * E_EDGES;
  float* out0 = GxB + (size_t)C * G4 * E_EDGES;
  float* hnG = out0 + outElems;                 // 4 * NN*HH (2 parities x 2 dirs)
  float* cnG = hnG + 4 * NN * HH;               // 2 * NN*HH
  float* cSt = cnG + 2 * NN * HH;
  float* cDt = cSt + (size_t)T_STEPS * NN;
  int* flags = (int*)(cDt + (size_t)T_STEPS * NN);

  (void)hipMemsetAsync(flags, 0, NWG * FSTRIDE * sizeof(int), stream);
  count_kernel<<<dim3(T_STEPS), 128, 0, stream>>>(src, dst, cSt, cDt);

  for (int layer = 0; layer < 2; ++layer) {
    const float* Wih = layer ? Wih1 : Wih0;
    const float* Whh = layer ? Whh1 : Whh0;
    const float* bb = layer ? b1 : b0;
    const float* In = layer ? out0 : x;
    float* outT = layer ? out : out0;
    (void)hipMemsetAsync(hnG, 0, 4 * NN * HH * sizeof(float), stream);
    (void)hipMemsetAsync(cnG, 0, 2 * NN * HH * sizeof(float), stream);
    for (int t0 = 0; t0 < T_STEPS; t0 += C) {
      if (layer == 0) {
        gates_gemm<64><<<dim3(16, C), 256, 0, stream>>>(In, Wih, bb, GxF, 0, t0, C);
        gates_gemm<64><<<dim3(16, C), 256, 0, stream>>>(In, Wih + (size_t)G4 * 64, bb + G4, GxB, 1, t0, C);
      } else {
        gates_gemm<512><<<dim3(16, C), 256, 0, stream>>>(In, Wih, bb, GxF, 0, t0, C);
        gates_gemm<512><<<dim3(16, C), 256, 0, stream>>>(In, Wih + (size_t)G4 * 512, bb + G4, GxB, 1, t0, C);
      }
      const float* gxF = GxF; const float* gxB = GxB;
      const float* whF = Whh; const float* whB = Whh + (size_t)G4 * HH;
      const int* psrc = src; const int* pdst = dst;
      const float* pcS = cSt; const float* pcD = cDt;
      float* phn = hnG; float* pcn = cnG; float* pout = outT;
      int a_t0 = t0, a_ns = C, a_rb = layer * T_STEPS + t0;
      int* pfl = flags;
      void* args[15] = {&gxF, &gxB, &whF, &whB, &psrc, &pdst, &pcS, &pcD,
                        &phn, &pcn, &pout, &a_t0, &a_ns, &a_rb, &pfl};
      hipLaunchCooperativeKernel((const void*)recur_kernel, dim3(NWG), dim3(TPB),
                                 args, 0, stream);
    }
  }
}

// Round 8
// 10318.391 us; speedup vs baseline: 1.3373x; 1.3306x over previous
//
#include <hip/hip_runtime.h>

#define T_STEPS 512
#define E_EDGES 128
#define NN 32
#define HH 256
#define G4 1024   // 4*H
#define NWG 64    // 2 dirs * 32 slots
#define TPB 256
#define FSTRIDE 16  // ints between flags (64B cachelines)

typedef __attribute__((ext_vector_type(8))) short s8v;     // 8 bf16 (4 VGPR)
typedef __attribute__((ext_vector_type(4))) float f4v;     // MFMA acc

__device__ __forceinline__ float fsig(float x) {
  x = fminf(fmaxf(x, -30.f), 30.f);
  return 1.f / (1.f + __expf(-x));
}
__device__ __forceinline__ float ftanh(float x) {
  float xc = fminf(fmaxf(x, -15.f), 15.f);
  float e = __expf(2.f * xc);
  return (e - 1.f) / (e + 1.f);
}
__device__ __forceinline__ float b2f(short s) {
  return __uint_as_float(((unsigned)(unsigned short)s) << 16);
}

// ---------------- prep: per-step CSR (edges sorted by dst), both dirs -----
__global__ __launch_bounds__(128) void prep_kernel(const int* __restrict__ src,
    const int* __restrict__ dst, int* __restrict__ eord, int* __restrict__ eoff) {
  __shared__ int de0[E_EDGES], de1[E_EDGES], off0[NN + 1], off1[NN + 1];
  const int t = blockIdx.x, e = threadIdx.x;
  de0[e] = dst[t * E_EDGES + e];   // dir0 uses step r = t
  de1[e] = src[t * E_EDGES + e];   // dir1 uses step r = 511 - t
  __syncthreads();
  if (e == 0) {
    int c[NN];
    for (int i = 0; i < NN; ++i) c[i] = 0;
    for (int i = 0; i < E_EDGES; ++i) c[de0[i]]++;
    int s = 0;
    for (int i = 0; i < NN; ++i) { off0[i] = s; s += c[i]; }
    off0[NN] = E_EDGES;
  }
  if (e == 1) {
    int c[NN];
    for (int i = 0; i < NN; ++i) c[i] = 0;
    for (int i = 0; i < E_EDGES; ++i) c[de1[i]]++;
    int s = 0;
    for (int i = 0; i < NN; ++i) { off1[i] = s; s += c[i]; }
    off1[NN] = E_EDGES;
  }
  __syncthreads();
  // deterministic stable rank
  int d0 = de0[e], r0 = 0, d1 = de1[e], r1 = 0;
  for (int i = 0; i < e; ++i) {
    r0 += (de0[i] == d0);
    r1 += (de1[i] == d1);
  }
  eord[((size_t)0 * T_STEPS + t) * E_EDGES + off0[d0] + r0] = e;
  eord[((size_t)1 * T_STEPS + (T_STEPS - 1 - t)) * E_EDGES + off1[d1] + r1] = e;
  if (e < NN + 1) {
    eoff[((size_t)0 * T_STEPS + t) * (NN + 1) + e] = off0[e];
    eoff[((size_t)1 * T_STEPS + (T_STEPS - 1 - t)) * (NN + 1) + e] = off1[e];
  }
}

// ---------------- feed-forward gates GEMM -----------------------------
// Output layout: Gx[slot][lt][gate][e][jj8] (per-recur-WG contiguous blocks)
template <int M>
__global__ __launch_bounds__(256) void gates_gemm(
    const float* __restrict__ In, const float* __restrict__ W,
    const float* __restrict__ b, float* __restrict__ Gx, int reverse, int t0,
    int Cs) {
  __shared__ float Wsh[64][68];
  __shared__ float Xsh[128][68];
  const int tid = threadIdx.x;
  const int k0 = blockIdx.x * 64;
  const int lt = blockIdx.y;
  const int t = t0 + lt;
  const int tsrc = reverse ? (T_STEPS - 1 - t) : t;
  const float* Inb = In + (size_t)tsrc * E_EDGES * M;

  const int ty = tid >> 4;
  const int tx = tid & 15;

  float acc[4][8];
#pragma unroll
  for (int i = 0; i < 4; ++i) {
    float bv = b[k0 + ty * 4 + i];
#pragma unroll
    for (int j = 0; j < 8; ++j) acc[i][j] = bv;
  }

  for (int m0 = 0; m0 < M; m0 += 64) {
    __syncthreads();
#pragma unroll
    for (int p = 0; p < 4; ++p) {
      int r = (tid >> 4) + 16 * p;
      int c4 = tid & 15;
      float4 v = *(const float4*)(W + (size_t)(k0 + r) * M + m0 + c4 * 4);
      *(float4*)(&Wsh[r][c4 * 4]) = v;
    }
#pragma unroll
    for (int p = 0; p < 8; ++p) {
      int r = (tid >> 4) + 16 * p;
      int c4 = tid & 15;
      float4 v = *(const float4*)(Inb + (size_t)r * M + m0 + c4 * 4);
      *(float4*)(&Xsh[r][c4 * 4]) = v;
    }
    __syncthreads();
#pragma unroll 4
    for (int mm4 = 0; mm4 < 16; ++mm4) {
      float4 wv4[4], xv4[8];
#pragma unroll
      for (int i = 0; i < 4; ++i) wv4[i] = *(const float4*)(&Wsh[ty * 4 + i][mm4 * 4]);
#pragma unroll
      for (int j = 0; j < 8; ++j) xv4[j] = *(const float4*)(&Xsh[tx + 16 * j][mm4 * 4]);
#pragma unroll
      for (int i = 0; i < 4; ++i)
#pragma unroll
        for (int j = 0; j < 8; ++j) {
          acc[i][j] = __fmaf_rn(wv4[i].x, xv4[j].x, acc[i][j]);
          acc[i][j] = __fmaf_rn(wv4[i].y, xv4[j].y, acc[i][j]);
          acc[i][j] = __fmaf_rn(wv4[i].z, xv4[j].z, acc[i][j]);
          acc[i][j] = __fmaf_rn(wv4[i].w, xv4[j].w, acc[i][j]);
        }
    }
  }
  {
    const int kb = k0 + ty * 4;
    const int gate = kb >> 8;
    const int ch = kb & 255;
    const int slot = ch >> 3;
    const int jj0 = ch & 7;
    float* gbase = Gx + ((((size_t)slot * Cs + lt) * 4 + gate) * E_EDGES) * 8 + jj0;
#pragma unroll
    for (int j = 0; j < 8; ++j) {
      int e = tx + 16 * j;
      *(float4*)(gbase + (size_t)e * 8) =
          make_float4(acc[0][j], acc[1][j], acc[2][j], acc[3][j]);
    }
  }
}

// ---------------- recurrence: MFMA z + CSR gather + flag barrier ------
__global__ __launch_bounds__(TPB) void recur_kernel(
    const float* __restrict__ GxF, const float* __restrict__ GxB,
    const float* __restrict__ WhhF, const float* __restrict__ WhhB,
    const int* __restrict__ src, const int* __restrict__ dst,
    const int* __restrict__ eord, const int* __restrict__ eoff,
    float* hnG, float* cnG, float* outBase,
    int t0, int nsteps, int roundBase, int* flags) {
  // bf16 hi/lo fragment stores: [hl][k>>3][row(32)+pad][8 elems]
  __shared__ short WsB[2][32][33][8];   // Whh slice (A), ~33.8KB
  __shared__ short hnB[2][32][33][8];   // hn (B), ~33.8KB
  __shared__ float zF[32][33];          // z[gc][node]
  __shared__ float hE[E_EDGES][8];      // per-edge h
  __shared__ float cE[E_EDGES][8];      // per-edge c
  __shared__ float cnL[NN][9];
  __shared__ int eordL[E_EDGES];
  __shared__ int eoffL[NN + 1];
  __shared__ int mfmaOK;

  const int tid = threadIdx.x;
  const int wg = blockIdx.x;
  const int dir = wg >> 5;
  const int slot = wg & 31;
  const int j0 = slot * 8;
  const float* Gx = dir ? GxB : GxF;
  const float* Whh = dir ? WhhB : WhhF;
  const int* seA = dir ? dst : src;
  float* cnGd = cnG + (size_t)dir * NN * HH;

  // --- one-time: stage Whh slice as bf16 hi/lo fragments ---
  {
    int gc = tid >> 3;
    int g = gc >> 3, jj2 = gc & 7;
    const float* wr = Whh + ((size_t)(g * HH) + j0 + jj2) * HH;
    int c0 = (tid & 7) * 32;
    for (int kk = 0; kk < 32; ++kk) {
      int k = c0 + kk;
      float f = wr[k];
      unsigned fb = __float_as_uint(f);
      unsigned hb = fb & 0xFFFF0000u;
      float lof = f - __uint_as_float(hb);
      WsB[0][k >> 3][gc][k & 7] = (short)(hb >> 16);
      WsB[1][k >> 3][gc][k & 7] = (short)(__float_as_uint(lof) >> 16);
    }
  }
  { // cell state
    int n = tid >> 3, jj = tid & 7;
    cnL[n][jj] = cnGd[n * HH + j0 + jj];
  }
  // --- one-time: MFMA layout self-test (exact integer check) ---
  if (tid < 64) {
    s8v ta, tb;
    const int rr = tid & 15, kh = (tid >> 4) * 8;
#pragma unroll
    for (int i = 0; i < 8; ++i) {
      int k = kh + i;
      ta[i] = (short)(__float_as_uint((float)((rr + 2 * k) & 7)) >> 16);
      tb[i] = (short)(__float_as_uint((float)(((3 * k + rr) & 7) - 3)) >> 16);
    }
    f4v tacc = {0.f, 0.f, 0.f, 0.f};
    tacc = __builtin_amdgcn_mfma_f32_16x16x32_bf16(ta, tb, tacc, 0, 0, 0);
    bool ok = true;
    const int col = tid & 15, rbase = (tid >> 4) * 4;
#pragma unroll
    for (int g2 = 0; g2 < 4; ++g2) {
      int row = rbase + g2;
      float ex = 0.f;
      for (int k = 0; k < 32; ++k)
        ex += (float)((row + 2 * k) & 7) * (float)(((3 * k + col) & 7) - 3);
      ok &= (tacc[g2] == ex);
    }
    unsigned long long bb = __ballot(ok);
    if (tid == 0) mfmaOK = (bb == 0xFFFFFFFFFFFFFFFFull) ? 1 : 0;
  }
  __syncthreads();
  const bool useMfma = (mfmaOK != 0);

  const int e = tid >> 1, jh = tid & 1;  // edge phase mapping
  const float* gxWG = Gx + (size_t)slot * nsteps * 4096 + (e * 8 + jh * 4);

  for (int rl = 0; rl < nsteps; ++rl) {
    const int r = t0 + rl;
    const int tv = dir ? (T_STEPS - 1 - r) : r;

    // --- P0: issue all global loads for this step (hide under poll) ---
    const int sec = seA[tv * E_EDGES + e];
    int eoV = 0, eofV = 0;
    if (tid < E_EDGES) eoV = eord[((size_t)dir * T_STEPS + r) * E_EDGES + tid];
    else if (tid < E_EDGES + NN + 1)
      eofV = eoff[((size_t)dir * T_STEPS + r) * (NN + 1) + (tid - E_EDGES)];
    const float* gp = gxWG + (size_t)rl * 4096;
    float4 gxi = *(const float4*)(gp + 0 * 1024);
    float4 gxf = *(const float4*)(gp + 1 * 1024);
    float4 gxg = *(const float4*)(gp + 2 * 1024);
    float4 gxo = *(const float4*)(gp + 3 * 1024);

    // --- P1: poll (relaxed coherent spin) ---
    if (rl > 0 && tid < 64) {
      const int target = roundBase + rl;
      int* fp = flags + (dir * 32 + (tid & 31)) * FSTRIDE;
      int guard = 0;
      for (;;) {
        int fv = __hip_atomic_load(fp, __ATOMIC_RELAXED, __HIP_MEMORY_SCOPE_AGENT);
        if (__all(fv >= target)) break;
        __builtin_amdgcn_s_sleep(1);
        if (++guard > (1 << 22)) break;
      }
    }
    __syncthreads();

    // --- P2: stage hn -> bf16 hi/lo fragments; stage CSR lists ---
    {
      const unsigned long long* hnRd = (const unsigned long long*)
          (hnG + (size_t)((r & 1) * 2 + dir) * NN * HH);
#pragma unroll
      for (int p = 0; p < 16; ++p) {
        int idx = tid + 256 * p;
        int n = idx >> 7, c2 = idx & 127;
        unsigned long long uv = __hip_atomic_load(hnRd + (size_t)n * 128 + c2,
            __ATOMIC_RELAXED, __HIP_MEMORY_SCOPE_AGENT);
        unsigned u0 = (unsigned)uv, u1 = (unsigned)(uv >> 32);
        unsigned h0 = u0 & 0xFFFF0000u, h1 = u1 & 0xFFFF0000u;
        float l0f = __uint_as_float(u0) - __uint_as_float(h0);
        float l1f = __uint_as_float(u1) - __uint_as_float(h1);
        unsigned hw = h1 | (u0 >> 16);
        unsigned lw = (__float_as_uint(l1f) & 0xFFFF0000u) |
                      (__float_as_uint(l0f) >> 16);
        int k = c2 * 2;
        ((unsigned*)&hnB[0][k >> 3][n][0])[(k & 7) >> 1] = hw;
        ((unsigned*)&hnB[1][k >> 3][n][0])[(k & 7) >> 1] = lw;
      }
      if (tid < E_EDGES) eordL[tid] = eoV;
      else if (tid < E_EDGES + NN + 1) eoffL[tid - E_EDGES] = eofV;
    }
    __syncthreads();

    // --- P3: z = Whh_slice @ hn^T via MFMA (wave 0), hi/lo 3-combo ---
    if (useMfma) {
      if (tid < 64) {
        const int lh = tid >> 4, ll = tid & 15;
        f4v a00 = {0,0,0,0}, a01 = {0,0,0,0}, a10 = {0,0,0,0}, a11 = {0,0,0,0};
        f4v b00 = {0,0,0,0}, b01 = {0,0,0,0}, b10 = {0,0,0,0}, b11 = {0,0,0,0};
#pragma unroll
        for (int kb = 0; kb < 8; ++kb) {
          s8v wh0 = *(const s8v*)&WsB[0][kb * 4 + lh][ll][0];
          s8v wh1 = *(const s8v*)&WsB[0][kb * 4 + lh][16 + ll][0];
          s8v wl0 = *(const s8v*)&WsB[1][kb * 4 + lh][ll][0];
          s8v wl1 = *(const s8v*)&WsB[1][kb * 4 + lh][16 + ll][0];
          s8v hh0 = *(const s8v*)&hnB[0][kb * 4 + lh][ll][0];
          s8v hh1 = *(const s8v*)&hnB[0][kb * 4 + lh][16 + ll][0];
          s8v hl0 = *(const s8v*)&hnB[1][kb * 4 + lh][ll][0];
          s8v hl1 = *(const s8v*)&hnB[1][kb * 4 + lh][16 + ll][0];
          a00 = __builtin_amdgcn_mfma_f32_16x16x32_bf16(wh0, hh0, a00, 0, 0, 0);
          a01 = __builtin_amdgcn_mfma_f32_16x16x32_bf16(wh0, hh1, a01, 0, 0, 0);
          a10 = __builtin_amdgcn_mfma_f32_16x16x32_bf16(wh1, hh0, a10, 0, 0, 0);
          a11 = __builtin_amdgcn_mfma_f32_16x16x32_bf16(wh1, hh1, a11, 0, 0, 0);
          b00 = __builtin_amdgcn_mfma_f32_16x16x32_bf16(wh0, hl0, b00, 0, 0, 0);
          b00 = __builtin_amdgcn_mfma_f32_16x16x32_bf16(wl0, hh0, b00, 0, 0, 0);
          b01 = __builtin_amdgcn_mfma_f32_16x16x32_bf16(wh0, hl1, b01, 0, 0, 0);
          b01 = __builtin_amdgcn_mfma_f32_16x16x32_bf16(wl0, hh1, b01, 0, 0, 0);
          b10 = __builtin_amdgcn_mfma_f32_16x16x32_bf16(wh1, hl0, b10, 0, 0, 0);
          b10 = __builtin_amdgcn_mfma_f32_16x16x32_bf16(wl1, hh0, b10, 0, 0, 0);
          b11 = __builtin_amdgcn_mfma_f32_16x16x32_bf16(wh1, hl1, b11, 0, 0, 0);
          b11 = __builtin_amdgcn_mfma_f32_16x16x32_bf16(wl1, hh1, b11, 0, 0, 0);
        }
#pragma unroll
        for (int g2 = 0; g2 < 4; ++g2) {
          int rw = lh * 4 + g2;
          zF[rw][ll]           = a00[g2] + b00[g2];
          zF[rw][16 + ll]      = a01[g2] + b01[g2];
          zF[16 + rw][ll]      = a10[g2] + b10[g2];
          zF[16 + rw][16 + ll] = a11[g2] + b11[g2];
        }
      }
    } else {
      // correct-but-slow fallback (layout self-test failed)
      int n = tid & 31, gq = tid >> 5;
      float za[4] = {0.f, 0.f, 0.f, 0.f};
      for (int k = 0; k < 256; ++k) {
        int kb8 = k >> 3, el = k & 7;
        float hv = b2f(hnB[0][kb8][n][el]) + b2f(hnB[1][kb8][n][el]);
#pragma unroll
        for (int q = 0; q < 4; ++q) {
          int gc = gq * 4 + q;
          za[q] += (b2f(WsB[0][kb8][gc][el]) + b2f(WsB[1][kb8][gc][el])) * hv;
        }
      }
#pragma unroll
      for (int q = 0; q < 4; ++q) zF[gq * 4 + q][n] = za[q];
    }
    __syncthreads();

    // --- P5: edge phase: gates -> cell -> per-edge h,c into LDS ---
    float hq[4];
    {
      const float gi4[4] = {gxi.x, gxi.y, gxi.z, gxi.w};
      const float gf4[4] = {gxf.x, gxf.y, gxf.z, gxf.w};
      const float gg4[4] = {gxg.x, gxg.y, gxg.z, gxg.w};
      const float go4[4] = {gxo.x, gxo.y, gxo.z, gxo.w};
      float cq[4];
#pragma unroll
      for (int u = 0; u < 4; ++u) {
        int jj = jh * 4 + u;
        float gi = gi4[u] + zF[jj][sec];
        float gf = gf4[u] + zF[8 + jj][sec];
        float gv = gg4[u] + zF[16 + jj][sec];
        float go = go4[u] + zF[24 + jj][sec];
        float cv = fsig(gf) * cnL[sec][jj] + fsig(gi) * ftanh(gv);
        float hv = fsig(go) * ftanh(cv);
        hq[u] = hv;
        cq[u] = cv;
      }
      *(float4*)&hE[e][jh * 4] = make_float4(hq[0], hq[1], hq[2], hq[3]);
      *(float4*)&cE[e][jh * 4] = make_float4(cq[0], cq[1], cq[2], cq[3]);
    }
    __syncthreads();

    // --- P6: CSR gather -> node means; coherent hn store; flag ---
    {
      int n = tid >> 3, jj = tid & 7;
      int o0 = eoffL[n], o1 = eoffL[n + 1];
      float sh = 0.f, sc = 0.f;
      for (int o = o0; o < o1; ++o) {
        int ee = eordL[o];
        sh += hE[ee][jj];
        sc += cE[ee][jj];
      }
      int len = o1 - o0;
      float rdn = (len > 0) ? (1.f / (float)len) : 1.f;
      float* hnWr = hnG + (size_t)(((r + 1) & 1) * 2 + dir) * NN * HH;
      __hip_atomic_store(hnWr + n * HH + j0 + jj, sh * rdn,
                         __ATOMIC_RELAXED, __HIP_MEMORY_SCOPE_AGENT);
      cnL[n][jj] = sc * rdn;
    }
    __syncthreads();   // drains vmcnt(0): hn stores acked at coherence point
    if (tid == 0) {
      __hip_atomic_store(flags + (dir * 32 + slot) * FSTRIDE, roundBase + rl + 1,
                         __ATOMIC_RELAXED, __HIP_MEMORY_SCOPE_AGENT);
    }

    // --- P7: out store (fire-and-forget) ---
    {
      int tw = dir ? (T_STEPS - 1 - r) : r;
      *(float4*)(outBase + ((size_t)tw * E_EDGES + e) * 512 + dir * 256 + j0 + jh * 4)
          = make_float4(hq[0], hq[1], hq[2], hq[3]);
    }
  }

  { // persist cell state for next chunk
    int n = tid >> 3, jj = tid & 7;
    cnGd[n * HH + j0 + jj] = cnL[n][jj];
  }
}

// ---------------- host launcher ---------------------------------------
extern "C" void kernel_launch(void* const* d_in, const int* in_sizes, int n_in,
                              void* d_out, int out_size, void* d_ws, size_t ws_size,
                              hipStream_t stream) {
  const float* x = (const float*)d_in[0];
  const float* Wih0 = (const float*)d_in[1];
  const float* Whh0 = (const float*)d_in[2];
  const float* b0 = (const float*)d_in[3];
  const float* Wih1 = (const float*)d_in[4];
  const float* Whh1 = (const float*)d_in[5];
  const float* b1 = (const float*)d_in[6];
  const int* src = (const int*)d_in[7];
  const int* dst = (const int*)d_in[8];
  float* out = (float*)d_out;

  const size_t outElems = (size_t)T_STEPS * E_EDGES * 512;
  const size_t eordW = (size_t)2 * T_STEPS * E_EDGES;       // ints
  const size_t eoffW = (size_t)2 * T_STEPS * (NN + 1);      // ints
  int C = 512;
  while (C >= 1) {
    size_t need = (2 * (size_t)C * G4 * E_EDGES + outElems + 6 * (size_t)NN * HH +
                   eordW + eoffW + NWG * FSTRIDE + 256) * sizeof(float);
    if (need <= ws_size) break;
    C >>= 1;
  }
  if (C < 1) return;

  float* GxF = (float*)d_ws;
  float* GxB = GxF + (size_t)C * G4 * E_EDGES;
  float* out0 = GxB + (size_t)C * G4 * E_EDGES;
  float* hnG = out0 + outElems;                 // 4 * NN*HH (2 parities x 2 dirs)
  float* cnG = hnG + 4 * NN * HH;               // 2 * NN*HH
  int* eord = (int*)(cnG + 2 * NN * HH);
  int* eoff = eord + eordW;
  int* flags = eoff + eoffW;

  (void)hipMemsetAsync(flags, 0, NWG * FSTRIDE * sizeof(int), stream);
  prep_kernel<<<dim3(T_STEPS), 128, 0, stream>>>(src, dst, eord, eoff);

  for (int layer = 0; layer < 2; ++layer) {
    const float* Wih = layer ? Wih1 : Wih0;
    const float* Whh = layer ? Whh1 : Whh0;
    const float* bb = layer ? b1 : b0;
    const float* In = layer ? out0 : x;
    float* outT = layer ? out : out0;
    (void)hipMemsetAsync(hnG, 0, 4 * NN * HH * sizeof(float), stream);
    (void)hipMemsetAsync(cnG, 0, 2 * NN * HH * sizeof(float), stream);
    for (int t0 = 0; t0 < T_STEPS; t0 += C) {
      if (layer == 0) {
        gates_gemm<64><<<dim3(16, C), 256, 0, stream>>>(In, Wih, bb, GxF, 0, t0, C);
        gates_gemm<64><<<dim3(16, C), 256, 0, stream>>>(In, Wih + (size_t)G4 * 64, bb + G4, GxB, 1, t0, C);
      } else {
        gates_gemm<512><<<dim3(16, C), 256, 0, stream>>>(In, Wih, bb, GxF, 0, t0, C);
        gates_gemm<512><<<dim3(16, C), 256, 0, stream>>>(In, Wih + (size_t)G4 * 512, bb + G4, GxB, 1, t0, C);
      }
      const float* gxF = GxF; const float* gxB = GxB;
      const float* whF = Whh; const float* whB = Whh + (size_t)G4 * HH;
      const int* psrc = src; const int* pdst = dst;
      const int* peord = eord; const int* peoff = eoff;
      float* phn = hnG; float* pcn = cnG; float* pout = outT;
      int a_t0 = t0, a_ns = C, a_rb = layer * T_STEPS + t0;
      int* pfl = flags;
      void* args[15] = {&gxF, &gxB, &whF, &whB, &psrc, &pdst, &peord, &peoff,
                        &phn, &pcn, &pout, &a_t0, &a_ns, &a_rb, &pfl};
      hipLaunchCooperativeKernel((const void*)recur_kernel, dim3(NWG), dim3(TPB),
                                 args, 0, stream);
    }
  }
}